// Round 1
// 19356.096 us; speedup vs baseline: 1.8602x; 1.8602x over previous
//
#include <hip/hip_runtime.h>
#include <math.h>

#define T_STEPS 2048
#define BATCH   64
#define HDIM    512
#define GDIM    2048   // 4*H
#define INDIM   256
#define NBLK_RE 128    // recurrence workgroups PER LAYER (1 per 4 h-dims)

typedef _Float16 f16x8 __attribute__((ext_vector_type(8)));
typedef _Float16 f16x4 __attribute__((ext_vector_type(4)));
typedef float    f32x4 __attribute__((ext_vector_type(4)));

__device__ __forceinline__ float sigf(float x) { return 1.0f / (1.0f + __expf(-x)); }
__device__ __forceinline__ float tanh_fast(float x) {
    return 1.0f - 2.0f / (__expf(2.0f * x) + 1.0f);   // saturates correctly
}

// ---------------------------------------------------------------------------
// fp32 -> fp16 weight conversion (once per launch; 2 MB each)
// ---------------------------------------------------------------------------
__global__ __launch_bounds__(256) void cvt_f16(const float* __restrict__ src,
                                               _Float16* __restrict__ dst, int n4)
{
    int i = blockIdx.x * 256 + threadIdx.x;
    if (i < n4) {
        float4 v = ((const float4*)src)[i];
        f16x4 h;
        h[0] = (_Float16)v.x; h[1] = (_Float16)v.y;
        h[2] = (_Float16)v.z; h[3] = (_Float16)v.w;
        ((f16x4*)dst)[i] = h;
    }
}

// ---------------------------------------------------------------------------
// GEMM: C[t][n][b] = sum_k A(m=t*64+b, k) * Bw[n][k] + bias1[n] + bias2[n]
// Only layer-1 (K=256, fp32 A) uses this now; layer-2's xg GEMM is folded
// into the fused recurrence kernel.
// ---------------------------------------------------------------------------
template <int K, bool AF16>
__global__ __launch_bounds__(256) void gemm_xg(
    const void* __restrict__ Araw, const float* __restrict__ Bw,
    const float* __restrict__ bias1, const float* __restrict__ bias2,
    float* __restrict__ C)
{
    constexpr int BK = 32;
    __shared__ float As[BK][128];
    __shared__ float Bs[BK][128];
    const int tid = threadIdx.x;
    const int n0 = blockIdx.x * 128;
    const int m0 = blockIdx.y * 128;

    float acc[8][8];
#pragma unroll
    for (int i = 0; i < 8; i++)
#pragma unroll
        for (int j = 0; j < 8; j++) acc[i][j] = 0.0f;

    for (int k0 = 0; k0 < K; k0 += BK) {
#pragma unroll
        for (int l = 0; l < 4; l++) {
            int slot = tid + l * 256;       // 1024 slots = 128 rows x 8 k-quads
            int row = slot >> 3, k4 = slot & 7;
            if (!AF16) {
                const float4 v = *(const float4*)
                    ((const float*)Araw + (size_t)(m0 + row) * K + k0 + k4 * 4);
                As[k4 * 4 + 0][row] = v.x; As[k4 * 4 + 1][row] = v.y;
                As[k4 * 4 + 2][row] = v.z; As[k4 * 4 + 3][row] = v.w;
            } else {
                const uint2 u = *(const uint2*)
                    ((const _Float16*)Araw + (size_t)(m0 + row) * K + k0 + k4 * 4);
                f16x4 h = __builtin_bit_cast(f16x4, u);
                As[k4 * 4 + 0][row] = (float)h[0]; As[k4 * 4 + 1][row] = (float)h[1];
                As[k4 * 4 + 2][row] = (float)h[2]; As[k4 * 4 + 3][row] = (float)h[3];
            }
        }
#pragma unroll
        for (int l = 0; l < 4; l++) {
            int slot = tid + l * 256;
            int row = slot >> 3, k4 = slot & 7;
            const float4 v = *(const float4*)&Bw[(size_t)(n0 + row) * K + k0 + k4 * 4];
            Bs[k4 * 4 + 0][row] = v.x; Bs[k4 * 4 + 1][row] = v.y;
            Bs[k4 * 4 + 2][row] = v.z; Bs[k4 * 4 + 3][row] = v.w;
        }
        __syncthreads();

        const int tm = (tid & 15) * 8, tn = (tid >> 4) * 8;
#pragma unroll
        for (int kk = 0; kk < BK; kk++) {
            float a[8], b[8];
            *(float4*)&a[0] = *(float4*)&As[kk][tm];
            *(float4*)&a[4] = *(float4*)&As[kk][tm + 4];
            *(float4*)&b[0] = *(float4*)&Bs[kk][tn];
            *(float4*)&b[4] = *(float4*)&Bs[kk][tn + 4];
#pragma unroll
            for (int i = 0; i < 8; i++)
#pragma unroll
                for (int j = 0; j < 8; j++) acc[i][j] += a[i] * b[j];
        }
        __syncthreads();
    }

    const int tm = (tid & 15) * 8, tn = (tid >> 4) * 8;
    float bs[8];
#pragma unroll
    for (int j = 0; j < 8; j++) {
        int n = n0 + tn + j;
        bs[j] = bias1[n] + bias2[n];
    }
#pragma unroll
    for (int i = 0; i < 8; i++) {
        int m = m0 + tm + i;
        int t = m >> 6, b = m & 63;
#pragma unroll
        for (int j = 0; j < 8; j++) {
            int n = n0 + tn + j;
            C[((size_t)t * GDIM + n) * BATCH + b] = acc[i][j] + bs[j];
        }
    }
}

// ---------------------------------------------------------------------------
// Fused 2-layer MFMA LSTM recurrence. 256 WGs (1/CU): blocks 0..127 = layer 1,
// 128..255 = layer 2. Layer-2 folds W_ih2 @ h1[t] into its per-step MFMA
// (K=1024), eliminating the layer-2 xg GEMM; it trails layer-1 by one publish.
// h broadcast: publishes are agent-scope (write-through LLC) + vmcnt drain
// before the counter bump; CONSUMER loads are plain cached loads — every
// hbuf address is fresh per timestep (dispatch-start invalidate), so the
// reader's L2 can never hold a stale line, and 16 WGs/XCD share one L2 copy
// (LLC burst per step drops 16x vs agent-scope reads).
// ---------------------------------------------------------------------------
__global__ __launch_bounds__(256, 1) void lstm_fused(
    const float* __restrict__ xg,        // [nsteps][2048][64] (layer-1 only)
    const _Float16* __restrict__ Wf1,    // W_hh1 [2048][512] fp16
    const _Float16* __restrict__ Wf2i,   // W_ih2 [2048][512] fp16
    const _Float16* __restrict__ Wf2h,   // W_hh2 [2048][512] fp16
    const float* __restrict__ bih2,      // [2048]
    const float* __restrict__ bhh2,      // [2048]
    _Float16* __restrict__ hb1,          // [nsteps+1][64][512]
    _Float16* __restrict__ hb2,          // [nsteps+1][64][512]
    float* __restrict__ c1,              // [512][64]
    float* __restrict__ c2,              // [512][64]
    unsigned* __restrict__ ctr1,
    unsigned* __restrict__ ctr2,
    int nsteps)
{
    __shared__ float    gl[16][68];      // gate exchange, padded
    __shared__ _Float16 hsm[64][4];      // packed h per batch

    const int tid   = threadIdx.x;
    const int layer = blockIdx.x >> 7;
    const int wg    = blockIdx.x & (NBLK_RE - 1);
    const int j0    = wg * 4;
    const int wv    = tid >> 6;          // wave = M-tile (16 batches)
    const int ln    = tid & 63;
    const int l16   = ln & 15;
    const int quad  = ln >> 4;
    const int grow  = (l16 >> 2) * HDIM + j0 + (l16 & 3);
    const int du    = wv;                // update thread: dim j0+du, batch bu
    const int bu    = tid & 63;

    if (layer == 0) {
        // ------------------------- layer 1 -------------------------
        f16x8 Bf[16];
#pragma unroll
        for (int j = 0; j < 16; j++) {
            const uint4 u = *(const uint4*)&Wf1[(size_t)grow * HDIM + j * 32 + quad * 8];
            Bf[j] = __builtin_bit_cast(f16x8, u);
        }
        float c_reg = c1[(size_t)(j0 + du) * BATCH + bu];

        const size_t xo0 = (size_t)(0 * HDIM + j0 + du) * BATCH + bu;
        const size_t xo1 = (size_t)(1 * HDIM + j0 + du) * BATCH + bu;
        const size_t xo2 = (size_t)(2 * HDIM + j0 + du) * BATCH + bu;
        const size_t xo3 = (size_t)(3 * HDIM + j0 + du) * BATCH + bu;

        for (int t = 0; t < nsteps; t++) {
            const float* xgt = xg + (size_t)t * GDIM * BATCH;
            float x0 = xgt[xo0], x1 = xgt[xo1], x2 = xgt[xo2], x3 = xgt[xo3];

            if (t > 0) {
                const unsigned tgt = (unsigned)(NBLK_RE * t);
                while (__hip_atomic_load(ctr1, __ATOMIC_RELAXED,
                                         __HIP_MEMORY_SCOPE_AGENT) < tgt) {}
                __atomic_signal_fence(__ATOMIC_ACQUIRE);
            }

            const _Float16* hp = hb1 + (size_t)t * (BATCH * HDIM)
                               + (size_t)(16 * wv + l16) * HDIM + quad * 8;
            ulonglong2 a[16];
#pragma unroll
            for (int j = 0; j < 16; j++)
                a[j] = *(const ulonglong2*)(hp + j * 32);

            f32x4 acc0 = {0.f, 0.f, 0.f, 0.f}, acc1 = {0.f, 0.f, 0.f, 0.f};
#pragma unroll
            for (int j = 0; j < 16; j += 2) {
                acc0 = __builtin_amdgcn_mfma_f32_16x16x32_f16(
                    __builtin_bit_cast(f16x8, a[j]),     Bf[j],     acc0, 0, 0, 0);
                acc1 = __builtin_amdgcn_mfma_f32_16x16x32_f16(
                    __builtin_bit_cast(f16x8, a[j + 1]), Bf[j + 1], acc1, 0, 0, 0);
            }
            f32x4 d = acc0 + acc1;
            *(f32x4*)&gl[l16][16 * wv + quad * 4] = d;
            __syncthreads();

            {
                float si = gl[4 * 0 + du][bu] + x0;
                float sf = gl[4 * 1 + du][bu] + x1;
                float sg = gl[4 * 2 + du][bu] + x2;
                float so = gl[4 * 3 + du][bu] + x3;
                c_reg = sigf(sf) * c_reg + sigf(si) * tanh_fast(sg);
                float h = sigf(so) * tanh_fast(c_reg);
                hsm[bu][du] = (_Float16)h;
            }
            __syncthreads();   // hsm ready; also protects gl before next D-write

            if (tid < 64) {
                unsigned long long pk = *(const unsigned long long*)&hsm[tid][0];
                unsigned long long* dst = (unsigned long long*)
                    (hb1 + (size_t)(t + 1) * (BATCH * HDIM) + (size_t)tid * HDIM + j0);
                __hip_atomic_store(dst, pk, __ATOMIC_RELAXED, __HIP_MEMORY_SCOPE_AGENT);
                if (t == nsteps - 1) {   // carry slot for next chunk
                    unsigned long long* dst0 = (unsigned long long*)
                        (hb1 + (size_t)tid * HDIM + j0);
                    __hip_atomic_store(dst0, pk, __ATOMIC_RELAXED, __HIP_MEMORY_SCOPE_AGENT);
                }
                if (tid == 0) {
                    asm volatile("s_waitcnt vmcnt(0)" ::: "memory");  // h at LLC
                    __hip_atomic_fetch_add(ctr1, 1u, __ATOMIC_RELAXED,
                                           __HIP_MEMORY_SCOPE_AGENT);
                }
            }
        }
        c1[(size_t)(j0 + du) * BATCH + bu] = c_reg;
    } else {
        // ------------------------- layer 2 -------------------------
        f16x8 Bh[16], Bi[16];
#pragma unroll
        for (int j = 0; j < 16; j++) {
            const uint4 uh = *(const uint4*)&Wf2h[(size_t)grow * HDIM + j * 32 + quad * 8];
            Bh[j] = __builtin_bit_cast(f16x8, uh);
            const uint4 ui = *(const uint4*)&Wf2i[(size_t)grow * HDIM + j * 32 + quad * 8];
            Bi[j] = __builtin_bit_cast(f16x8, ui);
        }
        float c_reg = c2[(size_t)(j0 + du) * BATCH + bu];
        const int dd = j0 + du;
        const float bi_ = bih2[0 * HDIM + dd] + bhh2[0 * HDIM + dd];
        const float bf_ = bih2[1 * HDIM + dd] + bhh2[1 * HDIM + dd];
        const float bg_ = bih2[2 * HDIM + dd] + bhh2[2 * HDIM + dd];
        const float bo_ = bih2[3 * HDIM + dd] + bhh2[3 * HDIM + dd];

        for (int t = 0; t < nsteps; t++) {
            f32x4 acc0 = {0.f, 0.f, 0.f, 0.f}, acc1 = {0.f, 0.f, 0.f, 0.f};

            // --- off-critical-path part first: W_ih2 @ h1[t] (slot t+1) ---
            {
                const unsigned tgt = (unsigned)(NBLK_RE * (t + 1));
                while (__hip_atomic_load(ctr1, __ATOMIC_RELAXED,
                                         __HIP_MEMORY_SCOPE_AGENT) < tgt) {}
                __atomic_signal_fence(__ATOMIC_ACQUIRE);
            }
            {
                const _Float16* hp = hb1 + (size_t)(t + 1) * (BATCH * HDIM)
                                   + (size_t)(16 * wv + l16) * HDIM + quad * 8;
                ulonglong2 a[16];
#pragma unroll
                for (int j = 0; j < 16; j++)
                    a[j] = *(const ulonglong2*)(hp + j * 32);
#pragma unroll
                for (int j = 0; j < 16; j += 2) {
                    acc0 = __builtin_amdgcn_mfma_f32_16x16x32_f16(
                        __builtin_bit_cast(f16x8, a[j]),     Bi[j],     acc0, 0, 0, 0);
                    acc1 = __builtin_amdgcn_mfma_f32_16x16x32_f16(
                        __builtin_bit_cast(f16x8, a[j + 1]), Bi[j + 1], acc1, 0, 0, 0);
                }
            }

            // --- critical path: own recurrence W_hh2 @ h2[t] ---
            if (t > 0) {
                const unsigned tgt = (unsigned)(NBLK_RE * t);
                while (__hip_atomic_load(ctr2, __ATOMIC_RELAXED,
                                         __HIP_MEMORY_SCOPE_AGENT) < tgt) {}
                __atomic_signal_fence(__ATOMIC_ACQUIRE);
            }
            {
                const _Float16* hp = hb2 + (size_t)t * (BATCH * HDIM)
                                   + (size_t)(16 * wv + l16) * HDIM + quad * 8;
                ulonglong2 a[16];
#pragma unroll
                for (int j = 0; j < 16; j++)
                    a[j] = *(const ulonglong2*)(hp + j * 32);
#pragma unroll
                for (int j = 0; j < 16; j += 2) {
                    acc0 = __builtin_amdgcn_mfma_f32_16x16x32_f16(
                        __builtin_bit_cast(f16x8, a[j]),     Bh[j],     acc0, 0, 0, 0);
                    acc1 = __builtin_amdgcn_mfma_f32_16x16x32_f16(
                        __builtin_bit_cast(f16x8, a[j + 1]), Bh[j + 1], acc1, 0, 0, 0);
                }
            }
            f32x4 d = acc0 + acc1;
            *(f32x4*)&gl[l16][16 * wv + quad * 4] = d;
            __syncthreads();

            {
                float si = gl[4 * 0 + du][bu] + bi_;
                float sf = gl[4 * 1 + du][bu] + bf_;
                float sg = gl[4 * 2 + du][bu] + bg_;
                float so = gl[4 * 3 + du][bu] + bo_;
                c_reg = sigf(sf) * c_reg + sigf(si) * tanh_fast(sg);
                float h = sigf(so) * tanh_fast(c_reg);
                hsm[bu][du] = (_Float16)h;
            }
            __syncthreads();

            if (tid < 64) {
                unsigned long long pk = *(const unsigned long long*)&hsm[tid][0];
                unsigned long long* dst = (unsigned long long*)
                    (hb2 + (size_t)(t + 1) * (BATCH * HDIM) + (size_t)tid * HDIM + j0);
                __hip_atomic_store(dst, pk, __ATOMIC_RELAXED, __HIP_MEMORY_SCOPE_AGENT);
                if (t == nsteps - 1) {
                    unsigned long long* dst0 = (unsigned long long*)
                        (hb2 + (size_t)tid * HDIM + j0);
                    __hip_atomic_store(dst0, pk, __ATOMIC_RELAXED, __HIP_MEMORY_SCOPE_AGENT);
                }
                if (tid == 0) {
                    asm volatile("s_waitcnt vmcnt(0)" ::: "memory");
                    __hip_atomic_fetch_add(ctr2, 1u, __ATOMIC_RELAXED,
                                           __HIP_MEMORY_SCOPE_AGENT);
                }
            }
        }
        c2[(size_t)(j0 + du) * BATCH + bu] = c_reg;
    }
}

// ---------------------------------------------------------------------------
// out[t*64+b] = sigmoid(dot(Wout, h2[t][b][:]) + bout); h2 fp16 [t][b][512]
// ---------------------------------------------------------------------------
__global__ __launch_bounds__(256) void out_kernel(
    const _Float16* __restrict__ h2, const float* __restrict__ Wout,
    const float* __restrict__ bout, float* __restrict__ out)
{
    const int t = blockIdx.x;
    const int q = threadIdx.x >> 6, b = threadIdx.x & 63;
    const _Float16* base = &h2[(size_t)t * (BATCH * HDIM) + (size_t)b * HDIM];
    float s = 0.0f;
#pragma unroll 8
    for (int k = q * 128; k < q * 128 + 128; k += 4) {
        const uint2 u = *(const uint2*)&base[k];
        f16x4 h = __builtin_bit_cast(f16x4, u);
        s += Wout[k] * (float)h[0] + Wout[k + 1] * (float)h[1]
           + Wout[k + 2] * (float)h[2] + Wout[k + 3] * (float)h[3];
    }
    __shared__ float red[4][64];
    red[q][b] = s;
    __syncthreads();
    if (q == 0) {
        float v = red[0][b] + red[1][b] + red[2][b] + red[3][b] + bout[0];
        out[t * BATCH + b] = sigf(v);
    }
}

// ---------------------------------------------------------------------------
static size_t req_bytes(int C) {
    return 131072                                // counters (128B-spaced pairs)
         + 2ull * HDIM * BATCH * 4               // c1, c2
         + 3ull * GDIM * HDIM * 2                // Wf1, Wf2i, Wf2h
         + 2ull * (size_t)(C + 1) * BATCH * HDIM * 2  // hbuf1, hbuf2
         + (size_t)C * GDIM * BATCH * 4;         // xg (layer-1 only)
}

extern "C" void kernel_launch(void* const* d_in, const int* in_sizes, int n_in,
                              void* d_out, int out_size, void* d_ws, size_t ws_size,
                              hipStream_t stream)
{
    const float* x    = (const float*)d_in[0];
    const float* Wih1 = (const float*)d_in[1];
    const float* Whh1 = (const float*)d_in[2];
    const float* bih1 = (const float*)d_in[3];
    const float* bhh1 = (const float*)d_in[4];
    const float* Wih2 = (const float*)d_in[5];
    const float* Whh2 = (const float*)d_in[6];
    const float* bih2 = (const float*)d_in[7];
    const float* bhh2 = (const float*)d_in[8];
    const float* Wout = (const float*)d_in[9];
    const float* bout = (const float*)d_in[10];
    float* out = (float*)d_out;

    int C = 8;
    const int cands[] = {2048, 1024, 512, 256, 128, 64, 32, 16, 8};
    for (int i = 0; i < 9; i++)
        if (req_bytes(cands[i]) <= ws_size) { C = cands[i]; break; }

    char* p = (char*)d_ws;
    unsigned*  ctr  = (unsigned*)p;                 p += 131072;
    float*     c1   = (float*)p;                    p += (size_t)HDIM * BATCH * 4;
    float*     c2   = (float*)p;                    p += (size_t)HDIM * BATCH * 4;
    _Float16*  Wf1  = (_Float16*)p;                 p += (size_t)GDIM * HDIM * 2;
    _Float16*  Wf2i = (_Float16*)p;                 p += (size_t)GDIM * HDIM * 2;
    _Float16*  Wf2h = (_Float16*)p;                 p += (size_t)GDIM * HDIM * 2;
    _Float16*  hb1  = (_Float16*)p;                 p += (size_t)(C + 1) * BATCH * HDIM * 2;
    _Float16*  hb2  = (_Float16*)p;                 p += (size_t)(C + 1) * BATCH * HDIM * 2;
    float*     xg   = (float*)p;

    // zero counters + c-state (contiguous) and the two h carry slots
    hipMemsetAsync(ctr, 0, 131072 + 2ull * HDIM * BATCH * 4, stream);
    hipMemsetAsync(hb1, 0, (size_t)BATCH * HDIM * 2, stream);
    hipMemsetAsync(hb2, 0, (size_t)BATCH * HDIM * 2, stream);

    // fp16 weights
    cvt_f16<<<dim3(GDIM * HDIM / 4 / 256), dim3(256), 0, stream>>>(Whh1, Wf1, GDIM * HDIM / 4);
    cvt_f16<<<dim3(GDIM * HDIM / 4 / 256), dim3(256), 0, stream>>>(Wih2, Wf2i, GDIM * HDIM / 4);
    cvt_f16<<<dim3(GDIM * HDIM / 4 / 256), dim3(256), 0, stream>>>(Whh2, Wf2h, GDIM * HDIM / 4);

    const _Float16* h2r = hb2 + (size_t)BATCH * HDIM;   // slots 1..C
    int cidx = 0;

    for (int t0 = 0; t0 < T_STEPS; t0 += C, cidx++) {
        gemm_xg<INDIM, false><<<dim3(GDIM / 128, C * BATCH / 128), dim3(256), 0, stream>>>(
            x + (size_t)t0 * BATCH * INDIM, Wih1, bih1, bhh1, xg);

        unsigned* c1p = ctr + (size_t)cidx * 64;   // 256B-spaced per chunk
        unsigned* c2p = c1p + 32;                  // 128B from c1p: no false sharing
        void* args[] = {(void*)&xg, (void*)&Wf1, (void*)&Wf2i, (void*)&Wf2h,
                        (void*)&bih2, (void*)&bhh2, (void*)&hb1, (void*)&hb2,
                        (void*)&c1, (void*)&c2, (void*)&c1p, (void*)&c2p, (void*)&C};
        hipLaunchCooperativeKernel((void*)lstm_fused, dim3(2 * NBLK_RE), dim3(256),
                                   args, 0, stream);

        out_kernel<<<dim3(C), dim3(256), 0, stream>>>(h2r, Wout, bout,
                                                      out + (size_t)t0 * BATCH);
    }

    (void)in_sizes; (void)n_in; (void)out_size;
}

// Round 2
// 13715.846 us; speedup vs baseline: 2.6251x; 1.4112x over previous
//
#include <hip/hip_runtime.h>
#include <math.h>

#define T_STEPS 2048
#define BATCH   64
#define HDIM    512
#define GDIM    2048   // 4*H
#define INDIM   256
#define NBLK_RE 128    // recurrence workgroups PER LAYER (1 per 4 h-dims)

typedef _Float16 f16x8 __attribute__((ext_vector_type(8)));
typedef _Float16 f16x4 __attribute__((ext_vector_type(4)));
typedef float    f32x4 __attribute__((ext_vector_type(4)));

__device__ __forceinline__ float sigf(float x) { return 1.0f / (1.0f + __expf(-x)); }
__device__ __forceinline__ float tanh_fast(float x) {
    return 1.0f - 2.0f / (__expf(2.0f * x) + 1.0f);   // saturates correctly
}

// ---------------------------------------------------------------------------
// fp32 -> fp16 conversion (weights once per launch; x once, 67 MB)
// ---------------------------------------------------------------------------
__global__ __launch_bounds__(256) void cvt_f16(const float* __restrict__ src,
                                               _Float16* __restrict__ dst, int n4)
{
    int i = blockIdx.x * 256 + threadIdx.x;
    if (i < n4) {
        float4 v = ((const float4*)src)[i];
        f16x4 h;
        h[0] = (_Float16)v.x; h[1] = (_Float16)v.y;
        h[2] = (_Float16)v.z; h[3] = (_Float16)v.w;
        ((f16x4*)dst)[i] = h;
    }
}

// ---------------------------------------------------------------------------
// Parallel flag-array barrier: producer WG stores flag[wg] = absolute step
// (one flag per 64B line, plain agent-scope store after vmcnt drain);
// consumers poll all 128 flags in parallel (one per lane) and combine with
// __syncthreads_and. Replaces the 128-deep serialized fetch_add chain.
// ---------------------------------------------------------------------------
__device__ __forceinline__ void wait_flags(const unsigned* __restrict__ flags,
                                           unsigned tgt, int tid)
{
    for (;;) {
        unsigned f = tgt;
        if (tid < NBLK_RE)
            f = __hip_atomic_load(flags + (size_t)tid * 16,
                                  __ATOMIC_RELAXED, __HIP_MEMORY_SCOPE_AGENT);
        if (__syncthreads_and((int)(f >= tgt))) break;
    }
    __atomic_signal_fence(__ATOMIC_ACQUIRE);
}

// ---------------------------------------------------------------------------
// Fully-fused 2-layer MFMA LSTM. 256 WGs (1/CU): blocks 0..127 = layer 1,
// 128..255 = layer 2. BOTH input GEMMs are folded into the recurrence:
// layer-1 adds W_ih1 @ x_t (K=256, fp16 x) and layer-2 adds W_ih2 @ h1[t]
// (K=512) as extra MFMAs issued BEFORE the flag wait (hidden in spin slack).
// No xg buffer, no separate GEMM kernel, single dispatch for all T=2048.
// h broadcast: agent-scope publishes (write-through LLC) + per-wave vmcnt
// drain + barrier before the flag store; consumer h loads are plain cached
// loads (every hbuf address fresh per step within the dispatch).
// Flags hold ABSOLUTE step numbers so chunked fallback needs no reset.
// ---------------------------------------------------------------------------
__global__ __launch_bounds__(256, 1) void lstm_fused(
    const _Float16* __restrict__ xh,     // [nsteps][64][256] fp16 (chunk base)
    const _Float16* __restrict__ Wf1h,   // W_hh1 [2048][512]
    const _Float16* __restrict__ Wf1i,   // W_ih1 [2048][256]
    const _Float16* __restrict__ Wf2i,   // W_ih2 [2048][512]
    const _Float16* __restrict__ Wf2h,   // W_hh2 [2048][512]
    const float* __restrict__ bih1, const float* __restrict__ bhh1,
    const float* __restrict__ bih2, const float* __restrict__ bhh2,
    _Float16* __restrict__ hb1,          // [nsteps+1][64][512]
    _Float16* __restrict__ hb2,
    float* __restrict__ c1,              // [512][64]
    float* __restrict__ c2,
    unsigned* __restrict__ flag1,        // [128] @ 64B stride
    unsigned* __restrict__ flag2,
    int nsteps, unsigned t0a)            // t0a = absolute first step of chunk
{
    __shared__ float gl[16][68];         // gate exchange, padded

    const int tid   = threadIdx.x;
    const int layer = blockIdx.x >> 7;
    const int wg    = blockIdx.x & (NBLK_RE - 1);
    const int j0    = wg * 4;
    const int wv    = tid >> 6;          // wave = M-tile (16 batches)
    const int ln    = tid & 63;
    const int l16   = ln & 15;
    const int quad  = ln >> 4;
    const int grow  = (l16 >> 2) * HDIM + j0 + (l16 & 3);
    const int du    = wv;                // update thread: dim j0+du, batch bu
    const int bu    = tid & 63;
    const int dd    = j0 + du;

    if (layer == 0) {
        // ------------------------- layer 1 -------------------------
        f16x8 Bh[16], Bx[8];
#pragma unroll
        for (int j = 0; j < 16; j++) {
            const uint4 u = *(const uint4*)&Wf1h[(size_t)grow * HDIM + j * 32 + quad * 8];
            Bh[j] = __builtin_bit_cast(f16x8, u);
        }
#pragma unroll
        for (int j = 0; j < 8; j++) {
            const uint4 u = *(const uint4*)&Wf1i[(size_t)grow * INDIM + j * 32 + quad * 8];
            Bx[j] = __builtin_bit_cast(f16x8, u);
        }
        float c_reg = c1[(size_t)dd * BATCH + bu];
        const float bi_ = bih1[0 * HDIM + dd] + bhh1[0 * HDIM + dd];
        const float bf_ = bih1[1 * HDIM + dd] + bhh1[1 * HDIM + dd];
        const float bg_ = bih1[2 * HDIM + dd] + bhh1[2 * HDIM + dd];
        const float bo_ = bih1[3 * HDIM + dd] + bhh1[3 * HDIM + dd];

        for (int t = 0; t < nsteps; t++) {
            f32x4 acc0 = {0.f, 0.f, 0.f, 0.f}, acc1 = {0.f, 0.f, 0.f, 0.f};

            // --- x contribution first (no dependency; hides in spin slack) ---
            {
                const _Float16* xp = xh + ((size_t)t * BATCH + 16 * wv + l16) * INDIM
                                   + quad * 8;
                ulonglong2 ax[8];
#pragma unroll
                for (int j = 0; j < 8; j++)
                    ax[j] = *(const ulonglong2*)(xp + j * 32);
#pragma unroll
                for (int j = 0; j < 8; j += 2) {
                    acc0 = __builtin_amdgcn_mfma_f32_16x16x32_f16(
                        __builtin_bit_cast(f16x8, ax[j]),     Bx[j],     acc0, 0, 0, 0);
                    acc1 = __builtin_amdgcn_mfma_f32_16x16x32_f16(
                        __builtin_bit_cast(f16x8, ax[j + 1]), Bx[j + 1], acc1, 0, 0, 0);
                }
            }

            // --- critical path: W_hh1 @ h1[t] ---
            wait_flags(flag1, t0a + (unsigned)t, tid);
            {
                const _Float16* hp = hb1 + (size_t)t * (BATCH * HDIM)
                                   + (size_t)(16 * wv + l16) * HDIM + quad * 8;
                ulonglong2 a[16];
#pragma unroll
                for (int j = 0; j < 16; j++)
                    a[j] = *(const ulonglong2*)(hp + j * 32);
#pragma unroll
                for (int j = 0; j < 16; j += 2) {
                    acc0 = __builtin_amdgcn_mfma_f32_16x16x32_f16(
                        __builtin_bit_cast(f16x8, a[j]),     Bh[j],     acc0, 0, 0, 0);
                    acc1 = __builtin_amdgcn_mfma_f32_16x16x32_f16(
                        __builtin_bit_cast(f16x8, a[j + 1]), Bh[j + 1], acc1, 0, 0, 0);
                }
            }
            f32x4 d = acc0 + acc1;
            *(f32x4*)&gl[l16][16 * wv + quad * 4] = d;
            __syncthreads();

            {
                float si = gl[4 * 0 + du][bu] + bi_;
                float sf = gl[4 * 1 + du][bu] + bf_;
                float sg = gl[4 * 2 + du][bu] + bg_;
                float so = gl[4 * 3 + du][bu] + bo_;
                c_reg = sigf(sf) * c_reg + sigf(si) * tanh_fast(sg);
                float h = sigf(so) * tanh_fast(c_reg);
                // direct per-thread publish (2B, agent scope)
                unsigned short hv = __builtin_bit_cast(unsigned short, (_Float16)h);
                unsigned short* dst = (unsigned short*)
                    (hb1 + (size_t)(t + 1) * (BATCH * HDIM) + (size_t)bu * HDIM + dd);
                __hip_atomic_store(dst, hv, __ATOMIC_RELAXED, __HIP_MEMORY_SCOPE_AGENT);
                if (t == nsteps - 1) {   // carry slot for next chunk
                    unsigned short* dst0 = (unsigned short*)
                        (hb1 + (size_t)bu * HDIM + dd);
                    __hip_atomic_store(dst0, hv, __ATOMIC_RELAXED, __HIP_MEMORY_SCOPE_AGENT);
                }
            }
            asm volatile("s_waitcnt vmcnt(0)" ::: "memory");   // h at LLC (per wave)
            __syncthreads();                                   // all 4 waves drained
            if (tid == 0)
                __hip_atomic_store(flag1 + (size_t)wg * 16, t0a + (unsigned)t + 1u,
                                   __ATOMIC_RELAXED, __HIP_MEMORY_SCOPE_AGENT);
        }
        c1[(size_t)dd * BATCH + bu] = c_reg;
    } else {
        // ------------------------- layer 2 -------------------------
        f16x8 Bh[16], Bi[16];
#pragma unroll
        for (int j = 0; j < 16; j++) {
            const uint4 uh = *(const uint4*)&Wf2h[(size_t)grow * HDIM + j * 32 + quad * 8];
            Bh[j] = __builtin_bit_cast(f16x8, uh);
            const uint4 ui = *(const uint4*)&Wf2i[(size_t)grow * HDIM + j * 32 + quad * 8];
            Bi[j] = __builtin_bit_cast(f16x8, ui);
        }
        float c_reg = c2[(size_t)dd * BATCH + bu];
        const float bi_ = bih2[0 * HDIM + dd] + bhh2[0 * HDIM + dd];
        const float bf_ = bih2[1 * HDIM + dd] + bhh2[1 * HDIM + dd];
        const float bg_ = bih2[2 * HDIM + dd] + bhh2[2 * HDIM + dd];
        const float bo_ = bih2[3 * HDIM + dd] + bhh2[3 * HDIM + dd];

        for (int t = 0; t < nsteps; t++) {
            f32x4 acc0 = {0.f, 0.f, 0.f, 0.f}, acc1 = {0.f, 0.f, 0.f, 0.f};

            // --- W_ih2 @ h1[t+1] (off own critical path) ---
            wait_flags(flag1, t0a + (unsigned)t + 1u, tid);
            {
                const _Float16* hp = hb1 + (size_t)(t + 1) * (BATCH * HDIM)
                                   + (size_t)(16 * wv + l16) * HDIM + quad * 8;
                ulonglong2 a[16];
#pragma unroll
                for (int j = 0; j < 16; j++)
                    a[j] = *(const ulonglong2*)(hp + j * 32);
#pragma unroll
                for (int j = 0; j < 16; j += 2) {
                    acc0 = __builtin_amdgcn_mfma_f32_16x16x32_f16(
                        __builtin_bit_cast(f16x8, a[j]),     Bi[j],     acc0, 0, 0, 0);
                    acc1 = __builtin_amdgcn_mfma_f32_16x16x32_f16(
                        __builtin_bit_cast(f16x8, a[j + 1]), Bi[j + 1], acc1, 0, 0, 0);
                }
            }

            // --- critical path: W_hh2 @ h2[t] ---
            wait_flags(flag2, t0a + (unsigned)t, tid);
            {
                const _Float16* hp = hb2 + (size_t)t * (BATCH * HDIM)
                                   + (size_t)(16 * wv + l16) * HDIM + quad * 8;
                ulonglong2 a[16];
#pragma unroll
                for (int j = 0; j < 16; j++)
                    a[j] = *(const ulonglong2*)(hp + j * 32);
#pragma unroll
                for (int j = 0; j < 16; j += 2) {
                    acc0 = __builtin_amdgcn_mfma_f32_16x16x32_f16(
                        __builtin_bit_cast(f16x8, a[j]),     Bh[j],     acc0, 0, 0, 0);
                    acc1 = __builtin_amdgcn_mfma_f32_16x16x32_f16(
                        __builtin_bit_cast(f16x8, a[j + 1]), Bh[j + 1], acc1, 0, 0, 0);
                }
            }
            f32x4 d = acc0 + acc1;
            *(f32x4*)&gl[l16][16 * wv + quad * 4] = d;
            __syncthreads();

            {
                float si = gl[4 * 0 + du][bu] + bi_;
                float sf = gl[4 * 1 + du][bu] + bf_;
                float sg = gl[4 * 2 + du][bu] + bg_;
                float so = gl[4 * 3 + du][bu] + bo_;
                c_reg = sigf(sf) * c_reg + sigf(si) * tanh_fast(sg);
                float h = sigf(so) * tanh_fast(c_reg);
                unsigned short hv = __builtin_bit_cast(unsigned short, (_Float16)h);
                unsigned short* dst = (unsigned short*)
                    (hb2 + (size_t)(t + 1) * (BATCH * HDIM) + (size_t)bu * HDIM + dd);
                __hip_atomic_store(dst, hv, __ATOMIC_RELAXED, __HIP_MEMORY_SCOPE_AGENT);
                if (t == nsteps - 1) {
                    unsigned short* dst0 = (unsigned short*)
                        (hb2 + (size_t)bu * HDIM + dd);
                    __hip_atomic_store(dst0, hv, __ATOMIC_RELAXED, __HIP_MEMORY_SCOPE_AGENT);
                }
            }
            asm volatile("s_waitcnt vmcnt(0)" ::: "memory");
            __syncthreads();
            if (tid == 0)
                __hip_atomic_store(flag2 + (size_t)wg * 16, t0a + (unsigned)t + 1u,
                                   __ATOMIC_RELAXED, __HIP_MEMORY_SCOPE_AGENT);
        }
        c2[(size_t)dd * BATCH + bu] = c_reg;
    }
}

// ---------------------------------------------------------------------------
// out[t*64+b] = sigmoid(dot(Wout, h2[t][b][:]) + bout); h2 fp16 [t][b][512]
// ---------------------------------------------------------------------------
__global__ __launch_bounds__(256) void out_kernel(
    const _Float16* __restrict__ h2, const float* __restrict__ Wout,
    const float* __restrict__ bout, float* __restrict__ out)
{
    const int t = blockIdx.x;
    const int q = threadIdx.x >> 6, b = threadIdx.x & 63;
    const _Float16* base = &h2[(size_t)t * (BATCH * HDIM) + (size_t)b * HDIM];
    float s = 0.0f;
#pragma unroll 8
    for (int k = q * 128; k < q * 128 + 128; k += 4) {
        const uint2 u = *(const uint2*)&base[k];
        f16x4 h = __builtin_bit_cast(f16x4, u);
        s += Wout[k] * (float)h[0] + Wout[k + 1] * (float)h[1]
           + Wout[k + 2] * (float)h[2] + Wout[k + 3] * (float)h[3];
    }
    __shared__ float red[4][64];
    red[q][b] = s;
    __syncthreads();
    if (q == 0) {
        float v = red[0][b] + red[1][b] + red[2][b] + red[3][b] + bout[0];
        out[t * BATCH + b] = sigf(v);
    }
}

// ---------------------------------------------------------------------------
static size_t req_bytes(int C) {
    return 65536                                      // flag arrays
         + 2ull * HDIM * BATCH * 4                    // c1, c2
         + 3ull * GDIM * HDIM * 2                     // Wf1h, Wf2i, Wf2h
         + (size_t)GDIM * INDIM * 2                   // Wf1i
         + (size_t)T_STEPS * BATCH * INDIM * 2        // xh (full sequence)
         + 2ull * (size_t)(C + 1) * BATCH * HDIM * 2; // hb1, hb2
}

extern "C" void kernel_launch(void* const* d_in, const int* in_sizes, int n_in,
                              void* d_out, int out_size, void* d_ws, size_t ws_size,
                              hipStream_t stream)
{
    const float* x    = (const float*)d_in[0];
    const float* Wih1 = (const float*)d_in[1];
    const float* Whh1 = (const float*)d_in[2];
    const float* bih1 = (const float*)d_in[3];
    const float* bhh1 = (const float*)d_in[4];
    const float* Wih2 = (const float*)d_in[5];
    const float* Whh2 = (const float*)d_in[6];
    const float* bih2 = (const float*)d_in[7];
    const float* bhh2 = (const float*)d_in[8];
    const float* Wout = (const float*)d_in[9];
    const float* bout = (const float*)d_in[10];
    float* out = (float*)d_out;

    int C = 8;
    const int cands[] = {2048, 1024, 512, 256, 128, 64, 32, 16, 8};
    for (int i = 0; i < 9; i++)
        if (req_bytes(cands[i]) <= ws_size) { C = cands[i]; break; }

    char* p = (char*)d_ws;
    unsigned*  flag1 = (unsigned*)p;                p += 32768;
    unsigned*  flag2 = (unsigned*)p;                p += 32768;
    float*     c1    = (float*)p;                   p += (size_t)HDIM * BATCH * 4;
    float*     c2    = (float*)p;                   p += (size_t)HDIM * BATCH * 4;
    _Float16*  Wf1h  = (_Float16*)p;                p += (size_t)GDIM * HDIM * 2;
    _Float16*  Wf1i  = (_Float16*)p;                p += (size_t)GDIM * INDIM * 2;
    _Float16*  Wf2i  = (_Float16*)p;                p += (size_t)GDIM * HDIM * 2;
    _Float16*  Wf2h  = (_Float16*)p;                p += (size_t)GDIM * HDIM * 2;
    _Float16*  xh    = (_Float16*)p;                p += (size_t)T_STEPS * BATCH * INDIM * 2;
    _Float16*  hb1   = (_Float16*)p;                p += (size_t)(C + 1) * BATCH * HDIM * 2;
    _Float16*  hb2   = (_Float16*)p;

    // zero flags + c-state (contiguous) and the two h carry slots
    hipMemsetAsync(flag1, 0, 65536 + 2ull * HDIM * BATCH * 4, stream);
    hipMemsetAsync(hb1, 0, (size_t)BATCH * HDIM * 2, stream);
    hipMemsetAsync(hb2, 0, (size_t)BATCH * HDIM * 2, stream);

    // fp16 conversions
    cvt_f16<<<dim3(GDIM * HDIM / 4 / 256), dim3(256), 0, stream>>>(Whh1, Wf1h, GDIM * HDIM / 4);
    cvt_f16<<<dim3(GDIM * INDIM / 4 / 256), dim3(256), 0, stream>>>(Wih1, Wf1i, GDIM * INDIM / 4);
    cvt_f16<<<dim3(GDIM * HDIM / 4 / 256), dim3(256), 0, stream>>>(Wih2, Wf2i, GDIM * HDIM / 4);
    cvt_f16<<<dim3(GDIM * HDIM / 4 / 256), dim3(256), 0, stream>>>(Whh2, Wf2h, GDIM * HDIM / 4);
    cvt_f16<<<dim3(T_STEPS * BATCH * INDIM / 4 / 256), dim3(256), 0, stream>>>(
        x, xh, T_STEPS * BATCH * INDIM / 4);

    const _Float16* h2r = hb2 + (size_t)BATCH * HDIM;   // slots 1..C

    for (int t0 = 0; t0 < T_STEPS; t0 += C) {
        const _Float16* xc = xh + (size_t)t0 * BATCH * INDIM;
        unsigned t0a = (unsigned)t0;
        void* args[] = {(void*)&xc, (void*)&Wf1h, (void*)&Wf1i, (void*)&Wf2i,
                        (void*)&Wf2h, (void*)&bih1, (void*)&bhh1, (void*)&bih2,
                        (void*)&bhh2, (void*)&hb1, (void*)&hb2, (void*)&c1,
                        (void*)&c2, (void*)&flag1, (void*)&flag2, (void*)&C,
                        (void*)&t0a};
        hipLaunchCooperativeKernel((void*)lstm_fused, dim3(2 * NBLK_RE), dim3(256),
                                   args, 0, stream);

        out_kernel<<<dim3(C), dim3(256), 0, stream>>>(h2r, Wout, bout,
                                                      out + (size_t)t0 * BATCH);
    }

    (void)in_sizes; (void)n_in; (void)out_size;
}

// Round 4
// 13218.350 us; speedup vs baseline: 2.7239x; 1.0376x over previous
//
#include <hip/hip_runtime.h>
#include <math.h>

#define T_STEPS 2048
#define BATCH   64
#define HDIM    512
#define GDIM    2048   // 4*H
#define INDIM   256
#define NBLK_RE 128    // recurrence workgroups PER LAYER (1 per 4 h-dims)
#define HB_STEP (HDIM * BATCH)   // elements per timestep slot

typedef _Float16 f16x8 __attribute__((ext_vector_type(8)));
typedef _Float16 f16x4 __attribute__((ext_vector_type(4)));
typedef float    f32x4 __attribute__((ext_vector_type(4)));

__device__ __forceinline__ float sigf(float x) { return 1.0f / (1.0f + __expf(-x)); }
__device__ __forceinline__ float tanh_fast(float x) {
    return 1.0f - 2.0f / (__expf(2.0f * x) + 1.0f);   // saturates correctly
}

// ---------------------------------------------------------------------------
// fp32 -> fp16 conversion (weights once per launch; x once, 67 MB)
// ---------------------------------------------------------------------------
__global__ __launch_bounds__(256) void cvt_f16(const float* __restrict__ src,
                                               _Float16* __restrict__ dst, int n4)
{
    int i = blockIdx.x * 256 + threadIdx.x;
    if (i < n4) {
        float4 v = ((const float4*)src)[i];
        f16x4 h;
        h[0] = (_Float16)v.x; h[1] = (_Float16)v.y;
        h[2] = (_Float16)v.z; h[3] = (_Float16)v.w;
        ((f16x4*)dst)[i] = h;
    }
}

// ---------------------------------------------------------------------------
// Parallel flag-array barrier (one flag per 64B line, absolute step values).
// ---------------------------------------------------------------------------
__device__ __forceinline__ void wait_flags(const unsigned* __restrict__ flags,
                                           unsigned tgt, int tid)
{
    for (;;) {
        unsigned f = tgt;
        if (tid < NBLK_RE)
            f = __hip_atomic_load(flags + (size_t)tid * 16,
                                  __ATOMIC_RELAXED, __HIP_MEMORY_SCOPE_AGENT);
        if (__syncthreads_and((int)(f >= tgt))) break;
    }
    __atomic_signal_fence(__ATOMIC_ACQUIRE);
}

// ---------------------------------------------------------------------------
// Fully-fused 2-layer MFMA LSTM. 256 WGs: blocks 0..127 = layer 1 (x GEMM
// folded, K=256 fp16), 128..255 = layer 2 (W_ih2@h1 folded, K=512).
// h buffers BATCH-MAJOR [t][b][512] (round-2 proven layout/numerics).
// Publish: round-1 proven pattern — h staged in hsm, wave 0 stores one
// PACKED 8B quad (4 dims) per batch, agent-scope; vmcnt drain in-wave, then
// tid0 stores the flag. This replaces round-2's per-thread 2B scatter that
// caused 4.2GB of HBM RMW write amplification.
// Consumers: plain cached 16B loads (proven rounds 1-2).
// ---------------------------------------------------------------------------
__global__ __launch_bounds__(256, 1) void lstm_fused(
    const _Float16* __restrict__ xh,     // [nsteps][64][256] fp16 (batch-major)
    const _Float16* __restrict__ Wf1h,   // W_hh1 [2048][512]
    const _Float16* __restrict__ Wf1i,   // W_ih1 [2048][256]
    const _Float16* __restrict__ Wf2i,   // W_ih2 [2048][512]
    const _Float16* __restrict__ Wf2h,   // W_hh2 [2048][512]
    const float* __restrict__ bih1, const float* __restrict__ bhh1,
    const float* __restrict__ bih2, const float* __restrict__ bhh2,
    _Float16* __restrict__ hb1,          // [nsteps+1][64][512] batch-major
    _Float16* __restrict__ hb2,
    float* __restrict__ c1,              // [512][64]
    float* __restrict__ c2,
    unsigned* __restrict__ flag1,        // [128] @ 64B stride
    unsigned* __restrict__ flag2,
    int nsteps, unsigned t0a)
{
    __shared__ float    gl[16][68];      // gate exchange, padded
    __shared__ _Float16 hsm[64][4];      // packed h per batch

    const int tid   = threadIdx.x;
    const int layer = blockIdx.x >> 7;
    const int wg    = blockIdx.x & (NBLK_RE - 1);
    const int j0    = wg * 4;
    const int wv    = tid >> 6;          // wave = M-tile (16 batches)
    const int ln    = tid & 63;
    const int l16   = ln & 15;
    const int quad  = ln >> 4;
    const int grow  = (l16 >> 2) * HDIM + j0 + (l16 & 3);
    const int du    = wv;                // update thread: dim j0+du, batch bu
    const int bu    = tid & 63;
    const int dd    = j0 + du;

    if (layer == 0) {
        // ------------------------- layer 1 -------------------------
        f16x8 Bh[16], Bx[8];
#pragma unroll
        for (int j = 0; j < 16; j++) {
            const uint4 u = *(const uint4*)&Wf1h[(size_t)grow * HDIM + j * 32 + quad * 8];
            Bh[j] = __builtin_bit_cast(f16x8, u);
        }
#pragma unroll
        for (int j = 0; j < 8; j++) {
            const uint4 u = *(const uint4*)&Wf1i[(size_t)grow * INDIM + j * 32 + quad * 8];
            Bx[j] = __builtin_bit_cast(f16x8, u);
        }
        float c_reg = c1[(size_t)dd * BATCH + bu];
        const float bi_ = bih1[0 * HDIM + dd] + bhh1[0 * HDIM + dd];
        const float bf_ = bih1[1 * HDIM + dd] + bhh1[1 * HDIM + dd];
        const float bg_ = bih1[2 * HDIM + dd] + bhh1[2 * HDIM + dd];
        const float bo_ = bih1[3 * HDIM + dd] + bhh1[3 * HDIM + dd];

        for (int t = 0; t < nsteps; t++) {
            f32x4 acc0 = {0.f, 0.f, 0.f, 0.f}, acc1 = {0.f, 0.f, 0.f, 0.f};

            // --- x contribution first (batch-major, 16B loads; no dep) ---
            {
                const _Float16* xp = xh + ((size_t)t * BATCH + 16 * wv + l16) * INDIM
                                   + quad * 8;
                ulonglong2 ax[8];
#pragma unroll
                for (int j = 0; j < 8; j++)
                    ax[j] = *(const ulonglong2*)(xp + j * 32);
#pragma unroll
                for (int j = 0; j < 8; j += 2) {
                    acc0 = __builtin_amdgcn_mfma_f32_16x16x32_f16(
                        __builtin_bit_cast(f16x8, ax[j]),     Bx[j],     acc0, 0, 0, 0);
                    acc1 = __builtin_amdgcn_mfma_f32_16x16x32_f16(
                        __builtin_bit_cast(f16x8, ax[j + 1]), Bx[j + 1], acc1, 0, 0, 0);
                }
            }

            // --- critical path: W_hh1 @ h1[t] ---
            wait_flags(flag1, t0a + (unsigned)t, tid);
            {
                const _Float16* hp = hb1 + (size_t)t * HB_STEP
                                   + (size_t)(16 * wv + l16) * HDIM + quad * 8;
                ulonglong2 a[16];
#pragma unroll
                for (int j = 0; j < 16; j++)
                    a[j] = *(const ulonglong2*)(hp + j * 32);
#pragma unroll
                for (int j = 0; j < 16; j += 2) {
                    acc0 = __builtin_amdgcn_mfma_f32_16x16x32_f16(
                        __builtin_bit_cast(f16x8, a[j]),     Bh[j],     acc0, 0, 0, 0);
                    acc1 = __builtin_amdgcn_mfma_f32_16x16x32_f16(
                        __builtin_bit_cast(f16x8, a[j + 1]), Bh[j + 1], acc1, 0, 0, 0);
                }
            }
            f32x4 d = acc0 + acc1;
            *(f32x4*)&gl[l16][16 * wv + quad * 4] = d;
            __syncthreads();

            {
                float si = gl[4 * 0 + du][bu] + bi_;
                float sf = gl[4 * 1 + du][bu] + bf_;
                float sg = gl[4 * 2 + du][bu] + bg_;
                float so = gl[4 * 3 + du][bu] + bo_;
                c_reg = sigf(sf) * c_reg + sigf(si) * tanh_fast(sg);
                float h = sigf(so) * tanh_fast(c_reg);
                hsm[bu][du] = (_Float16)h;
            }
            __syncthreads();   // hsm ready; also protects gl before next D-write

            // --- packed publish (wave 0): one 8B quad per batch ---
            if (tid < 64) {
                unsigned long long pk = *(const unsigned long long*)&hsm[tid][0];
                unsigned long long* dst = (unsigned long long*)
                    (hb1 + (size_t)(t + 1) * HB_STEP + (size_t)tid * HDIM + j0);
                __hip_atomic_store(dst, pk, __ATOMIC_RELAXED, __HIP_MEMORY_SCOPE_AGENT);
                if (t == nsteps - 1) {   // carry slot for next chunk
                    unsigned long long* dst0 = (unsigned long long*)
                        (hb1 + (size_t)tid * HDIM + j0);
                    __hip_atomic_store(dst0, pk, __ATOMIC_RELAXED, __HIP_MEMORY_SCOPE_AGENT);
                }
                if (tid == 0) {
                    asm volatile("s_waitcnt vmcnt(0)" ::: "memory");  // h at LLC
                    __hip_atomic_store(flag1 + (size_t)wg * 16, t0a + (unsigned)t + 1u,
                                       __ATOMIC_RELAXED, __HIP_MEMORY_SCOPE_AGENT);
                }
            }
        }
        c1[(size_t)dd * BATCH + bu] = c_reg;
    } else {
        // ------------------------- layer 2 -------------------------
        f16x8 Bh[16], Bi[16];
#pragma unroll
        for (int j = 0; j < 16; j++) {
            const uint4 uh = *(const uint4*)&Wf2h[(size_t)grow * HDIM + j * 32 + quad * 8];
            Bh[j] = __builtin_bit_cast(f16x8, uh);
            const uint4 ui = *(const uint4*)&Wf2i[(size_t)grow * HDIM + j * 32 + quad * 8];
            Bi[j] = __builtin_bit_cast(f16x8, ui);
        }
        float c_reg = c2[(size_t)dd * BATCH + bu];
        const float bi_ = bih2[0 * HDIM + dd] + bhh2[0 * HDIM + dd];
        const float bf_ = bih2[1 * HDIM + dd] + bhh2[1 * HDIM + dd];
        const float bg_ = bih2[2 * HDIM + dd] + bhh2[2 * HDIM + dd];
        const float bo_ = bih2[3 * HDIM + dd] + bhh2[3 * HDIM + dd];

        for (int t = 0; t < nsteps; t++) {
            f32x4 acc0 = {0.f, 0.f, 0.f, 0.f}, acc1 = {0.f, 0.f, 0.f, 0.f};

            // --- W_ih2 @ h1[t+1] (off own critical path) ---
            wait_flags(flag1, t0a + (unsigned)t + 1u, tid);
            {
                const _Float16* hp = hb1 + (size_t)(t + 1) * HB_STEP
                                   + (size_t)(16 * wv + l16) * HDIM + quad * 8;
                ulonglong2 a[16];
#pragma unroll
                for (int j = 0; j < 16; j++)
                    a[j] = *(const ulonglong2*)(hp + j * 32);
#pragma unroll
                for (int j = 0; j < 16; j += 2) {
                    acc0 = __builtin_amdgcn_mfma_f32_16x16x32_f16(
                        __builtin_bit_cast(f16x8, a[j]),     Bi[j],     acc0, 0, 0, 0);
                    acc1 = __builtin_amdgcn_mfma_f32_16x16x32_f16(
                        __builtin_bit_cast(f16x8, a[j + 1]), Bi[j + 1], acc1, 0, 0, 0);
                }
            }

            // --- critical path: W_hh2 @ h2[t] ---
            wait_flags(flag2, t0a + (unsigned)t, tid);
            {
                const _Float16* hp = hb2 + (size_t)t * HB_STEP
                                   + (size_t)(16 * wv + l16) * HDIM + quad * 8;
                ulonglong2 a[16];
#pragma unroll
                for (int j = 0; j < 16; j++)
                    a[j] = *(const ulonglong2*)(hp + j * 32);
#pragma unroll
                for (int j = 0; j < 16; j += 2) {
                    acc0 = __builtin_amdgcn_mfma_f32_16x16x32_f16(
                        __builtin_bit_cast(f16x8, a[j]),     Bh[j],     acc0, 0, 0, 0);
                    acc1 = __builtin_amdgcn_mfma_f32_16x16x32_f16(
                        __builtin_bit_cast(f16x8, a[j + 1]), Bh[j + 1], acc1, 0, 0, 0);
                }
            }
            f32x4 d = acc0 + acc1;
            *(f32x4*)&gl[l16][16 * wv + quad * 4] = d;
            __syncthreads();

            {
                float si = gl[4 * 0 + du][bu] + bi_;
                float sf = gl[4 * 1 + du][bu] + bf_;
                float sg = gl[4 * 2 + du][bu] + bg_;
                float so = gl[4 * 3 + du][bu] + bo_;
                c_reg = sigf(sf) * c_reg + sigf(si) * tanh_fast(sg);
                float h = sigf(so) * tanh_fast(c_reg);
                hsm[bu][du] = (_Float16)h;
            }
            __syncthreads();

            if (tid < 64) {
                unsigned long long pk = *(const unsigned long long*)&hsm[tid][0];
                unsigned long long* dst = (unsigned long long*)
                    (hb2 + (size_t)(t + 1) * HB_STEP + (size_t)tid * HDIM + j0);
                __hip_atomic_store(dst, pk, __ATOMIC_RELAXED, __HIP_MEMORY_SCOPE_AGENT);
                if (t == nsteps - 1) {
                    unsigned long long* dst0 = (unsigned long long*)
                        (hb2 + (size_t)tid * HDIM + j0);
                    __hip_atomic_store(dst0, pk, __ATOMIC_RELAXED, __HIP_MEMORY_SCOPE_AGENT);
                }
                if (tid == 0) {
                    asm volatile("s_waitcnt vmcnt(0)" ::: "memory");
                    __hip_atomic_store(flag2 + (size_t)wg * 16, t0a + (unsigned)t + 1u,
                                       __ATOMIC_RELAXED, __HIP_MEMORY_SCOPE_AGENT);
                }
            }
        }
        c2[(size_t)dd * BATCH + bu] = c_reg;
    }
}

// ---------------------------------------------------------------------------
// out[t*64+b] = sigmoid(dot(Wout, h2[t][b][:]) + bout); h2 fp16 [t][b][512]
// ---------------------------------------------------------------------------
__global__ __launch_bounds__(256) void out_kernel(
    const _Float16* __restrict__ h2, const float* __restrict__ Wout,
    const float* __restrict__ bout, float* __restrict__ out)
{
    const int t = blockIdx.x;
    const int q = threadIdx.x >> 6, b = threadIdx.x & 63;
    const _Float16* base = &h2[(size_t)t * HB_STEP + (size_t)b * HDIM];
    float s = 0.0f;
#pragma unroll 8
    for (int k = q * 128; k < q * 128 + 128; k += 4) {
        const uint2 u = *(const uint2*)&base[k];
        f16x4 h = __builtin_bit_cast(f16x4, u);
        s += Wout[k] * (float)h[0] + Wout[k + 1] * (float)h[1]
           + Wout[k + 2] * (float)h[2] + Wout[k + 3] * (float)h[3];
    }
    __shared__ float red[4][64];
    red[q][b] = s;
    __syncthreads();
    if (q == 0) {
        float v = red[0][b] + red[1][b] + red[2][b] + red[3][b] + bout[0];
        out[t * BATCH + b] = sigf(v);
    }
}

// ---------------------------------------------------------------------------
static size_t req_bytes(int C) {
    return 65536                                      // flag arrays
         + 2ull * HDIM * BATCH * 4                    // c1, c2
         + 3ull * GDIM * HDIM * 2                     // Wf1h, Wf2i, Wf2h
         + (size_t)GDIM * INDIM * 2                   // Wf1i
         + (size_t)T_STEPS * BATCH * INDIM * 2        // xh (full sequence)
         + 2ull * (size_t)(C + 1) * BATCH * HDIM * 2; // hb1, hb2
}

extern "C" void kernel_launch(void* const* d_in, const int* in_sizes, int n_in,
                              void* d_out, int out_size, void* d_ws, size_t ws_size,
                              hipStream_t stream)
{
    const float* x    = (const float*)d_in[0];
    const float* Wih1 = (const float*)d_in[1];
    const float* Whh1 = (const float*)d_in[2];
    const float* bih1 = (const float*)d_in[3];
    const float* bhh1 = (const float*)d_in[4];
    const float* Wih2 = (const float*)d_in[5];
    const float* Whh2 = (const float*)d_in[6];
    const float* bih2 = (const float*)d_in[7];
    const float* bhh2 = (const float*)d_in[8];
    const float* Wout = (const float*)d_in[9];
    const float* bout = (const float*)d_in[10];
    float* out = (float*)d_out;

    int C = 8;
    const int cands[] = {2048, 1024, 512, 256, 128, 64, 32, 16, 8};
    for (int i = 0; i < 9; i++)
        if (req_bytes(cands[i]) <= ws_size) { C = cands[i]; break; }

    char* p = (char*)d_ws;
    unsigned*  flag1 = (unsigned*)p;                p += 32768;
    unsigned*  flag2 = (unsigned*)p;                p += 32768;
    float*     c1    = (float*)p;                   p += (size_t)HDIM * BATCH * 4;
    float*     c2    = (float*)p;                   p += (size_t)HDIM * BATCH * 4;
    _Float16*  Wf1h  = (_Float16*)p;                p += (size_t)GDIM * HDIM * 2;
    _Float16*  Wf1i  = (_Float16*)p;                p += (size_t)GDIM * INDIM * 2;
    _Float16*  Wf2i  = (_Float16*)p;                p += (size_t)GDIM * HDIM * 2;
    _Float16*  Wf2h  = (_Float16*)p;                p += (size_t)GDIM * HDIM * 2;
    _Float16*  xh    = (_Float16*)p;                p += (size_t)T_STEPS * BATCH * INDIM * 2;
    _Float16*  hb1   = (_Float16*)p;                p += (size_t)(C + 1) * BATCH * HDIM * 2;
    _Float16*  hb2   = (_Float16*)p;

    // zero flags + c-state (contiguous) and the two h carry slots
    hipMemsetAsync(flag1, 0, 65536 + 2ull * HDIM * BATCH * 4, stream);
    hipMemsetAsync(hb1, 0, (size_t)BATCH * HDIM * 2, stream);
    hipMemsetAsync(hb2, 0, (size_t)BATCH * HDIM * 2, stream);

    // fp16 conversions
    cvt_f16<<<dim3(GDIM * HDIM / 4 / 256), dim3(256), 0, stream>>>(Whh1, Wf1h, GDIM * HDIM / 4);
    cvt_f16<<<dim3(GDIM * INDIM / 4 / 256), dim3(256), 0, stream>>>(Wih1, Wf1i, GDIM * INDIM / 4);
    cvt_f16<<<dim3(GDIM * HDIM / 4 / 256), dim3(256), 0, stream>>>(Wih2, Wf2i, GDIM * HDIM / 4);
    cvt_f16<<<dim3(GDIM * HDIM / 4 / 256), dim3(256), 0, stream>>>(Whh2, Wf2h, GDIM * HDIM / 4);
    cvt_f16<<<dim3(T_STEPS * BATCH * INDIM / 4 / 256), dim3(256), 0, stream>>>(
        x, xh, T_STEPS * BATCH * INDIM / 4);

    const _Float16* h2r = hb2 + (size_t)HB_STEP;   // slots 1..C

    for (int t0 = 0; t0 < T_STEPS; t0 += C) {
        const _Float16* xc = xh + (size_t)t0 * BATCH * INDIM;
        unsigned t0a = (unsigned)t0;
        void* args[] = {(void*)&xc, (void*)&Wf1h, (void*)&Wf1i, (void*)&Wf2i,
                        (void*)&Wf2h, (void*)&bih1, (void*)&bhh1, (void*)&bih2,
                        (void*)&bhh2, (void*)&hb1, (void*)&hb2, (void*)&c1,
                        (void*)&c2, (void*)&flag1, (void*)&flag2, (void*)&C,
                        (void*)&t0a};
        hipLaunchCooperativeKernel((void*)lstm_fused, dim3(2 * NBLK_RE), dim3(256),
                                   args, 0, stream);

        out_kernel<<<dim3(C), dim3(256), 0, stream>>>(h2r, Wout, bout,
                                                      out + (size_t)t0 * BATCH);
    }

    (void)in_sizes; (void)n_in; (void)out_size;
}

// Round 5
// 12591.866 us; speedup vs baseline: 2.8594x; 1.0498x over previous
//
#include <hip/hip_runtime.h>
#include <math.h>

#define T_STEPS 2048
#define BATCH   64
#define HDIM    512
#define GDIM    2048   // 4*H
#define INDIM   256
#define NBLK_RE 128    // recurrence workgroups PER LAYER (1 per 4 h-dims)
#define HB_STEP (HDIM * BATCH)   // elements per timestep slot

typedef _Float16 f16x8 __attribute__((ext_vector_type(8)));
typedef _Float16 f16x4 __attribute__((ext_vector_type(4)));
typedef float    f32x4 __attribute__((ext_vector_type(4)));

__device__ __forceinline__ float sigf(float x) { return 1.0f / (1.0f + __expf(-x)); }
__device__ __forceinline__ float tanh_fast(float x) {
    return 1.0f - 2.0f / (__expf(2.0f * x) + 1.0f);   // saturates correctly
}

// ---------------------------------------------------------------------------
// fp32 -> fp16 conversion (weights once per launch; x once, 67 MB)
// ---------------------------------------------------------------------------
__global__ __launch_bounds__(256) void cvt_f16(const float* __restrict__ src,
                                               _Float16* __restrict__ dst, int n4)
{
    int i = blockIdx.x * 256 + threadIdx.x;
    if (i < n4) {
        float4 v = ((const float4*)src)[i];
        f16x4 h;
        h[0] = (_Float16)v.x; h[1] = (_Float16)v.y;
        h[2] = (_Float16)v.z; h[3] = (_Float16)v.w;
        ((f16x4*)dst)[i] = h;
    }
}

// ---------------------------------------------------------------------------
// Wave-local barrier-free flag poll. Each lane loads 2 of the 128 per-WG
// flags (64B-strided); __all combines across the wave. NO __syncthreads in
// the loop (round-2/4's syncthreads_and poll quantized exit latency to 1-2
// extra iterations ~1us each — the measured +2us/step vs round-1).
// Producers: single plain agent store after vmcnt drain (no RMW chain).
// ---------------------------------------------------------------------------
__device__ __forceinline__ void wait_flags_wave(const unsigned* __restrict__ flags,
                                                unsigned tgt, int ln)
{
    const unsigned* p0 = flags + (size_t)ln * 16;          // ln = 0..63
    const unsigned* p1 = flags + (size_t)(ln + 64) * 16;
    for (;;) {
        unsigned f0 = __hip_atomic_load(p0, __ATOMIC_RELAXED, __HIP_MEMORY_SCOPE_AGENT);
        unsigned f1 = __hip_atomic_load(p1, __ATOMIC_RELAXED, __HIP_MEMORY_SCOPE_AGENT);
        if (__all((int)(f0 >= tgt) & (int)(f1 >= tgt))) break;
    }
    __atomic_signal_fence(__ATOMIC_ACQUIRE);
}

// ---------------------------------------------------------------------------
// Fully-fused 2-layer MFMA LSTM. 256 WGs: blocks 0..127 = layer 1 (x GEMM
// folded, K=256 fp16), 128..255 = layer 2 (W_ih2@h1 folded, K=512).
// h buffers BATCH-MAJOR [t][b][512]; packed 8B publish via hsm + wave 0
// (round-4 proven). Split MFMA accumulators: x-part and h-part chains are
// independent, so the post-wait h chain starts fresh.
// ---------------------------------------------------------------------------
__global__ __launch_bounds__(256, 1) void lstm_fused(
    const _Float16* __restrict__ xh,     // [nsteps][64][256] fp16 (batch-major)
    const _Float16* __restrict__ Wf1h,   // W_hh1 [2048][512]
    const _Float16* __restrict__ Wf1i,   // W_ih1 [2048][256]
    const _Float16* __restrict__ Wf2i,   // W_ih2 [2048][512]
    const _Float16* __restrict__ Wf2h,   // W_hh2 [2048][512]
    const float* __restrict__ bih1, const float* __restrict__ bhh1,
    const float* __restrict__ bih2, const float* __restrict__ bhh2,
    _Float16* __restrict__ hb1,          // [nsteps+1][64][512] batch-major
    _Float16* __restrict__ hb2,
    float* __restrict__ c1,              // [512][64]
    float* __restrict__ c2,
    unsigned* __restrict__ flag1,        // [128] @ 64B stride
    unsigned* __restrict__ flag2,
    int nsteps, unsigned t0a)
{
    __shared__ float    gl[16][68];      // gate exchange, padded
    __shared__ _Float16 hsm[64][4];      // packed h per batch

    const int tid   = threadIdx.x;
    const int layer = blockIdx.x >> 7;
    const int wg    = blockIdx.x & (NBLK_RE - 1);
    const int j0    = wg * 4;
    const int wv    = tid >> 6;          // wave = M-tile (16 batches)
    const int ln    = tid & 63;
    const int l16   = ln & 15;
    const int quad  = ln >> 4;
    const int grow  = (l16 >> 2) * HDIM + j0 + (l16 & 3);
    const int du    = wv;                // update thread: dim j0+du, batch bu
    const int bu    = tid & 63;
    const int dd    = j0 + du;

    if (layer == 0) {
        // ------------------------- layer 1 -------------------------
        f16x8 Bh[16], Bx[8];
#pragma unroll
        for (int j = 0; j < 16; j++) {
            const uint4 u = *(const uint4*)&Wf1h[(size_t)grow * HDIM + j * 32 + quad * 8];
            Bh[j] = __builtin_bit_cast(f16x8, u);
        }
#pragma unroll
        for (int j = 0; j < 8; j++) {
            const uint4 u = *(const uint4*)&Wf1i[(size_t)grow * INDIM + j * 32 + quad * 8];
            Bx[j] = __builtin_bit_cast(f16x8, u);
        }
        float c_reg = c1[(size_t)dd * BATCH + bu];
        const float bi_ = bih1[0 * HDIM + dd] + bhh1[0 * HDIM + dd];
        const float bf_ = bih1[1 * HDIM + dd] + bhh1[1 * HDIM + dd];
        const float bg_ = bih1[2 * HDIM + dd] + bhh1[2 * HDIM + dd];
        const float bo_ = bih1[3 * HDIM + dd] + bhh1[3 * HDIM + dd];

        for (int t = 0; t < nsteps; t++) {
            f32x4 ax0 = {0.f, 0.f, 0.f, 0.f}, ax1 = {0.f, 0.f, 0.f, 0.f};

            // --- x contribution first (independent accumulators; no dep) ---
            {
                const _Float16* xp = xh + ((size_t)t * BATCH + 16 * wv + l16) * INDIM
                                   + quad * 8;
                ulonglong2 ax[8];
#pragma unroll
                for (int j = 0; j < 8; j++)
                    ax[j] = *(const ulonglong2*)(xp + j * 32);
#pragma unroll
                for (int j = 0; j < 8; j += 2) {
                    ax0 = __builtin_amdgcn_mfma_f32_16x16x32_f16(
                        __builtin_bit_cast(f16x8, ax[j]),     Bx[j],     ax0, 0, 0, 0);
                    ax1 = __builtin_amdgcn_mfma_f32_16x16x32_f16(
                        __builtin_bit_cast(f16x8, ax[j + 1]), Bx[j + 1], ax1, 0, 0, 0);
                }
            }

            // --- critical path: W_hh1 @ h1[t] (fresh accumulator chains) ---
            wait_flags_wave(flag1, t0a + (unsigned)t, ln);
            f32x4 ah0 = {0.f, 0.f, 0.f, 0.f}, ah1 = {0.f, 0.f, 0.f, 0.f};
            f32x4 ah2 = {0.f, 0.f, 0.f, 0.f}, ah3 = {0.f, 0.f, 0.f, 0.f};
            {
                const _Float16* hp = hb1 + (size_t)t * HB_STEP
                                   + (size_t)(16 * wv + l16) * HDIM + quad * 8;
                ulonglong2 a[16];
#pragma unroll
                for (int j = 0; j < 16; j++)
                    a[j] = *(const ulonglong2*)(hp + j * 32);
#pragma unroll
                for (int j = 0; j < 16; j += 4) {
                    ah0 = __builtin_amdgcn_mfma_f32_16x16x32_f16(
                        __builtin_bit_cast(f16x8, a[j]),     Bh[j],     ah0, 0, 0, 0);
                    ah1 = __builtin_amdgcn_mfma_f32_16x16x32_f16(
                        __builtin_bit_cast(f16x8, a[j + 1]), Bh[j + 1], ah1, 0, 0, 0);
                    ah2 = __builtin_amdgcn_mfma_f32_16x16x32_f16(
                        __builtin_bit_cast(f16x8, a[j + 2]), Bh[j + 2], ah2, 0, 0, 0);
                    ah3 = __builtin_amdgcn_mfma_f32_16x16x32_f16(
                        __builtin_bit_cast(f16x8, a[j + 3]), Bh[j + 3], ah3, 0, 0, 0);
                }
            }
            f32x4 d = (ax0 + ax1) + ((ah0 + ah1) + (ah2 + ah3));
            *(f32x4*)&gl[l16][16 * wv + quad * 4] = d;
            __syncthreads();

            {
                float si = gl[4 * 0 + du][bu] + bi_;
                float sf = gl[4 * 1 + du][bu] + bf_;
                float sg = gl[4 * 2 + du][bu] + bg_;
                float so = gl[4 * 3 + du][bu] + bo_;
                c_reg = sigf(sf) * c_reg + sigf(si) * tanh_fast(sg);
                float h = sigf(so) * tanh_fast(c_reg);
                hsm[bu][du] = (_Float16)h;
            }
            __syncthreads();   // hsm ready; also protects gl before next D-write

            // --- packed publish (wave 0): one 8B quad per batch ---
            if (tid < 64) {
                unsigned long long pk = *(const unsigned long long*)&hsm[tid][0];
                unsigned long long* dst = (unsigned long long*)
                    (hb1 + (size_t)(t + 1) * HB_STEP + (size_t)tid * HDIM + j0);
                __hip_atomic_store(dst, pk, __ATOMIC_RELAXED, __HIP_MEMORY_SCOPE_AGENT);
                if (t == nsteps - 1) {   // carry slot for next chunk
                    unsigned long long* dst0 = (unsigned long long*)
                        (hb1 + (size_t)tid * HDIM + j0);
                    __hip_atomic_store(dst0, pk, __ATOMIC_RELAXED, __HIP_MEMORY_SCOPE_AGENT);
                }
                if (tid == 0) {
                    asm volatile("s_waitcnt vmcnt(0)" ::: "memory");  // h at LLC
                    __hip_atomic_store(flag1 + (size_t)wg * 16, t0a + (unsigned)t + 1u,
                                       __ATOMIC_RELAXED, __HIP_MEMORY_SCOPE_AGENT);
                }
            }
        }
        c1[(size_t)dd * BATCH + bu] = c_reg;
    } else {
        // ------------------------- layer 2 -------------------------
        f16x8 Bh[16], Bi[16];
#pragma unroll
        for (int j = 0; j < 16; j++) {
            const uint4 uh = *(const uint4*)&Wf2h[(size_t)grow * HDIM + j * 32 + quad * 8];
            Bh[j] = __builtin_bit_cast(f16x8, uh);
            const uint4 ui = *(const uint4*)&Wf2i[(size_t)grow * HDIM + j * 32 + quad * 8];
            Bi[j] = __builtin_bit_cast(f16x8, ui);
        }
        float c_reg = c2[(size_t)dd * BATCH + bu];
        const float bi_ = bih2[0 * HDIM + dd] + bhh2[0 * HDIM + dd];
        const float bf_ = bih2[1 * HDIM + dd] + bhh2[1 * HDIM + dd];
        const float bg_ = bih2[2 * HDIM + dd] + bhh2[2 * HDIM + dd];
        const float bo_ = bih2[3 * HDIM + dd] + bhh2[3 * HDIM + dd];

        for (int t = 0; t < nsteps; t++) {
            f32x4 ai0 = {0.f, 0.f, 0.f, 0.f}, ai1 = {0.f, 0.f, 0.f, 0.f};
            f32x4 ag0 = {0.f, 0.f, 0.f, 0.f}, ag1 = {0.f, 0.f, 0.f, 0.f};

            // --- W_ih2 @ h1[t+1] (independent accumulators) ---
            wait_flags_wave(flag1, t0a + (unsigned)t + 1u, ln);
            {
                const _Float16* hp = hb1 + (size_t)(t + 1) * HB_STEP
                                   + (size_t)(16 * wv + l16) * HDIM + quad * 8;
                ulonglong2 a[16];
#pragma unroll
                for (int j = 0; j < 16; j++)
                    a[j] = *(const ulonglong2*)(hp + j * 32);
#pragma unroll
                for (int j = 0; j < 16; j += 2) {
                    ai0 = __builtin_amdgcn_mfma_f32_16x16x32_f16(
                        __builtin_bit_cast(f16x8, a[j]),     Bi[j],     ai0, 0, 0, 0);
                    ai1 = __builtin_amdgcn_mfma_f32_16x16x32_f16(
                        __builtin_bit_cast(f16x8, a[j + 1]), Bi[j + 1], ai1, 0, 0, 0);
                }
            }

            // --- critical path: W_hh2 @ h2[t] ---
            wait_flags_wave(flag2, t0a + (unsigned)t, ln);
            {
                const _Float16* hp = hb2 + (size_t)t * HB_STEP
                                   + (size_t)(16 * wv + l16) * HDIM + quad * 8;
                ulonglong2 a[16];
#pragma unroll
                for (int j = 0; j < 16; j++)
                    a[j] = *(const ulonglong2*)(hp + j * 32);
#pragma unroll
                for (int j = 0; j < 16; j += 2) {
                    ag0 = __builtin_amdgcn_mfma_f32_16x16x32_f16(
                        __builtin_bit_cast(f16x8, a[j]),     Bh[j],     ag0, 0, 0, 0);
                    ag1 = __builtin_amdgcn_mfma_f32_16x16x32_f16(
                        __builtin_bit_cast(f16x8, a[j + 1]), Bh[j + 1], ag1, 0, 0, 0);
                }
            }
            f32x4 d = (ai0 + ai1) + (ag0 + ag1);
            *(f32x4*)&gl[l16][16 * wv + quad * 4] = d;
            __syncthreads();

            {
                float si = gl[4 * 0 + du][bu] + bi_;
                float sf = gl[4 * 1 + du][bu] + bf_;
                float sg = gl[4 * 2 + du][bu] + bg_;
                float so = gl[4 * 3 + du][bu] + bo_;
                c_reg = sigf(sf) * c_reg + sigf(si) * tanh_fast(sg);
                float h = sigf(so) * tanh_fast(c_reg);
                hsm[bu][du] = (_Float16)h;
            }
            __syncthreads();

            if (tid < 64) {
                unsigned long long pk = *(const unsigned long long*)&hsm[tid][0];
                unsigned long long* dst = (unsigned long long*)
                    (hb2 + (size_t)(t + 1) * HB_STEP + (size_t)tid * HDIM + j0);
                __hip_atomic_store(dst, pk, __ATOMIC_RELAXED, __HIP_MEMORY_SCOPE_AGENT);
                if (t == nsteps - 1) {
                    unsigned long long* dst0 = (unsigned long long*)
                        (hb2 + (size_t)tid * HDIM + j0);
                    __hip_atomic_store(dst0, pk, __ATOMIC_RELAXED, __HIP_MEMORY_SCOPE_AGENT);
                }
                if (tid == 0) {
                    asm volatile("s_waitcnt vmcnt(0)" ::: "memory");
                    __hip_atomic_store(flag2 + (size_t)wg * 16, t0a + (unsigned)t + 1u,
                                       __ATOMIC_RELAXED, __HIP_MEMORY_SCOPE_AGENT);
                }
            }
        }
        c2[(size_t)dd * BATCH + bu] = c_reg;
    }
}

// ---------------------------------------------------------------------------
// out[t*64+b] = sigmoid(dot(Wout, h2[t][b][:]) + bout); h2 fp16 [t][b][512]
// ---------------------------------------------------------------------------
__global__ __launch_bounds__(256) void out_kernel(
    const _Float16* __restrict__ h2, const float* __restrict__ Wout,
    const float* __restrict__ bout, float* __restrict__ out)
{
    const int t = blockIdx.x;
    const int q = threadIdx.x >> 6, b = threadIdx.x & 63;
    const _Float16* base = &h2[(size_t)t * HB_STEP + (size_t)b * HDIM];
    float s = 0.0f;
#pragma unroll 8
    for (int k = q * 128; k < q * 128 + 128; k += 4) {
        const uint2 u = *(const uint2*)&base[k];
        f16x4 h = __builtin_bit_cast(f16x4, u);
        s += Wout[k] * (float)h[0] + Wout[k + 1] * (float)h[1]
           + Wout[k + 2] * (float)h[2] + Wout[k + 3] * (float)h[3];
    }
    __shared__ float red[4][64];
    red[q][b] = s;
    __syncthreads();
    if (q == 0) {
        float v = red[0][b] + red[1][b] + red[2][b] + red[3][b] + bout[0];
        out[t * BATCH + b] = sigf(v);
    }
}

// ---------------------------------------------------------------------------
static size_t req_bytes(int C) {
    return 65536                                      // flag arrays
         + 2ull * HDIM * BATCH * 4                    // c1, c2
         + 3ull * GDIM * HDIM * 2                     // Wf1h, Wf2i, Wf2h
         + (size_t)GDIM * INDIM * 2                   // Wf1i
         + (size_t)T_STEPS * BATCH * INDIM * 2        // xh (full sequence)
         + 2ull * (size_t)(C + 1) * BATCH * HDIM * 2; // hb1, hb2
}

extern "C" void kernel_launch(void* const* d_in, const int* in_sizes, int n_in,
                              void* d_out, int out_size, void* d_ws, size_t ws_size,
                              hipStream_t stream)
{
    const float* x    = (const float*)d_in[0];
    const float* Wih1 = (const float*)d_in[1];
    const float* Whh1 = (const float*)d_in[2];
    const float* bih1 = (const float*)d_in[3];
    const float* bhh1 = (const float*)d_in[4];
    const float* Wih2 = (const float*)d_in[5];
    const float* Whh2 = (const float*)d_in[6];
    const float* bih2 = (const float*)d_in[7];
    const float* bhh2 = (const float*)d_in[8];
    const float* Wout = (const float*)d_in[9];
    const float* bout = (const float*)d_in[10];
    float* out = (float*)d_out;

    int C = 8;
    const int cands[] = {2048, 1024, 512, 256, 128, 64, 32, 16, 8};
    for (int i = 0; i < 9; i++)
        if (req_bytes(cands[i]) <= ws_size) { C = cands[i]; break; }

    char* p = (char*)d_ws;
    unsigned*  flag1 = (unsigned*)p;                p += 32768;
    unsigned*  flag2 = (unsigned*)p;                p += 32768;
    float*     c1    = (float*)p;                   p += (size_t)HDIM * BATCH * 4;
    float*     c2    = (float*)p;                   p += (size_t)HDIM * BATCH * 4;
    _Float16*  Wf1h  = (_Float16*)p;                p += (size_t)GDIM * HDIM * 2;
    _Float16*  Wf1i  = (_Float16*)p;                p += (size_t)GDIM * INDIM * 2;
    _Float16*  Wf2i  = (_Float16*)p;                p += (size_t)GDIM * HDIM * 2;
    _Float16*  Wf2h  = (_Float16*)p;                p += (size_t)GDIM * HDIM * 2;
    _Float16*  xh    = (_Float16*)p;                p += (size_t)T_STEPS * BATCH * INDIM * 2;
    _Float16*  hb1   = (_Float16*)p;                p += (size_t)(C + 1) * BATCH * HDIM * 2;
    _Float16*  hb2   = (_Float16*)p;

    // zero flags + c-state (contiguous) and the two h carry slots
    hipMemsetAsync(flag1, 0, 65536 + 2ull * HDIM * BATCH * 4, stream);
    hipMemsetAsync(hb1, 0, (size_t)BATCH * HDIM * 2, stream);
    hipMemsetAsync(hb2, 0, (size_t)BATCH * HDIM * 2, stream);

    // fp16 conversions
    cvt_f16<<<dim3(GDIM * HDIM / 4 / 256), dim3(256), 0, stream>>>(Whh1, Wf1h, GDIM * HDIM / 4);
    cvt_f16<<<dim3(GDIM * INDIM / 4 / 256), dim3(256), 0, stream>>>(Wih1, Wf1i, GDIM * INDIM / 4);
    cvt_f16<<<dim3(GDIM * HDIM / 4 / 256), dim3(256), 0, stream>>>(Wih2, Wf2i, GDIM * HDIM / 4);
    cvt_f16<<<dim3(GDIM * HDIM / 4 / 256), dim3(256), 0, stream>>>(Whh2, Wf2h, GDIM * HDIM / 4);
    cvt_f16<<<dim3(T_STEPS * BATCH * INDIM / 4 / 256), dim3(256), 0, stream>>>(
        x, xh, T_STEPS * BATCH * INDIM / 4);

    const _Float16* h2r = hb2 + (size_t)HB_STEP;   // slots 1..C

    for (int t0 = 0; t0 < T_STEPS; t0 += C) {
        const _Float16* xc = xh + (size_t)t0 * BATCH * INDIM;
        unsigned t0a = (unsigned)t0;
        void* args[] = {(void*)&xc, (void*)&Wf1h, (void*)&Wf1i, (void*)&Wf2i,
                        (void*)&Wf2h, (void*)&bih1, (void*)&bhh1, (void*)&bih2,
                        (void*)&bhh2, (void*)&hb1, (void*)&hb2, (void*)&c1,
                        (void*)&c2, (void*)&flag1, (void*)&flag2, (void*)&C,
                        (void*)&t0a};
        hipLaunchCooperativeKernel((void*)lstm_fused, dim3(2 * NBLK_RE), dim3(256),
                                   args, 0, stream);

        out_kernel<<<dim3(C), dim3(256), 0, stream>>>(h2r, Wout, bout,
                                                      out + (size_t)t0 * BATCH);
    }

    (void)in_sizes; (void)n_in; (void)out_size;
}